// Round 1
// baseline (512.723 us; speedup 1.0000x reference)
//
#include <hip/hip_runtime.h>
#include <stdint.h>

#define NB    16
#define NANCH 65536
#define NC    21
#define NCLS  20
#define TOPK  200
#define NBINS 2048
#define CAP   256

// ---------------- Kernel 1: softmax (classes 1..20) -> transposed scores ----
// scores[(b*20 + (c-1))*NANCH + n] = exp(conf[b,n,c]-m) / S
// S computed in numpy pairwise-sum order for n=21 to match the np reference.
__global__ __launch_bounds__(256) void softmax_scores_kernel(
    const float* __restrict__ conf, float* __restrict__ scores) {
  int a = blockIdx.x * 256 + threadIdx.x;  // [0, NB*NANCH)
  const float* row = conf + (long long)a * NC;
  float x[NC];
#pragma unroll
  for (int c = 0; c < NC; ++c) x[c] = row[c];
  float m = x[0];
#pragma unroll
  for (int c = 1; c < NC; ++c) m = fmaxf(m, x[c]);
  float e[NC];
#pragma unroll
  for (int c = 0; c < NC; ++c) e[c] = expf(x[c] - m);
  // numpy pairwise_sum for n=21: r[j]=a[j]+a[j+8]; tree; then += a[16..20]
  float r0 = e[0] + e[8],  r1 = e[1] + e[9],  r2 = e[2] + e[10], r3 = e[3] + e[11];
  float r4 = e[4] + e[12], r5 = e[5] + e[13], r6 = e[6] + e[14], r7 = e[7] + e[15];
  float S = ((r0 + r1) + (r2 + r3)) + ((r4 + r5) + (r6 + r7));
  S += e[16]; S += e[17]; S += e[18]; S += e[19]; S += e[20];
  int b = a >> 16;              // NANCH = 65536
  int n = a & (NANCH - 1);
  long long base = ((long long)b * NCLS) * NANCH + n;
#pragma unroll
  for (int c = 1; c < NC; ++c)
    scores[base + (long long)(c - 1) * NANCH] = e[c] / S;  // IEEE div, like np
}

// ---------------- Kernel 2: per-(b,c) top-200 + decode + NMS + output -------
// Linear-value 2-level histogram select over scores >= 0.05 (monotone binning
// => collected set is a superset of the exact top-200 incl. ties), 64-bit
// (score desc, idx asc) bitonic sort matching jax.lax.top_k tie-break, IoU
// adjacency bitmask + serial greedy scan, masked 5-float output rows.

constexpr float SCALE0 = 2048.0f / 0.95f;
constexpr float W0     = 0.95f / 2048.0f;
constexpr float SCALE1 = 2048.0f / W0;

__device__ __forceinline__ int bin0_of(float s) {
  int b = (int)((s - 0.05f) * SCALE0);
  return b < 0 ? 0 : (b > NBINS - 1 ? NBINS - 1 : b);
}
__device__ __forceinline__ int bin1_of(float s, float lo) {
  int b = (int)((s - lo) * SCALE1);
  return b < 0 ? 0 : (b > NBINS - 1 ? NBINS - 1 : b);
}

__global__ __launch_bounds__(256) void topk_nms_kernel(
    const float* __restrict__ scores, const float* __restrict__ loc,
    const float* __restrict__ anchors, float* __restrict__ out) {
  const int bc  = blockIdx.x;         // b*20 + (c-1)
  const int b   = bc / NCLS;
  const int tid = threadIdx.x;
  const float* col = scores + (long long)bc * NANCH;

  __shared__ unsigned int hist[NBINS];
  __shared__ unsigned long long cand[CAP];
  __shared__ float bx[TOPK][4];
  __shared__ float barea[TOPK];
  __shared__ float bscore[TOPK];
  __shared__ unsigned long long adj[TOPK][4];
  __shared__ unsigned char keepf[TOPK];
  __shared__ int s_sel0, s_sel1, s_cumabove, s_ncand;

  // ---- pass 0: 2048 linear bins over [0.05, 1.0], filtered s >= 0.05 ----
  for (int i = tid; i < NBINS; i += 256) hist[i] = 0;
  __syncthreads();
  for (int i = tid; i < NANCH; i += 256) {
    float s = col[i];
    if (s >= 0.05f) atomicAdd(&hist[bin0_of(s)], 1u);
  }
  __syncthreads();
  if (tid == 0) {
    unsigned int cum = 0; int sel = -1;
    for (int bin = NBINS - 1; bin >= 0; --bin) {
      unsigned int c = hist[bin];
      if (cum + c >= TOPK) { sel = bin; break; }
      cum += c;
    }
    s_sel0 = sel; s_cumabove = (int)cum;
  }
  __syncthreads();
  const int  sel0     = s_sel0;
  const bool fallback = (sel0 < 0);         // fewer than 200 scores >= 0.05
  const float lo = 0.05f + (float)sel0 * W0;

  // ---- pass 1: refine within bin sel0 (bin width ~4 ulps) ----
  int sel1 = 0;
  if (!fallback) {
    for (int i = tid; i < NBINS; i += 256) hist[i] = 0;
    __syncthreads();
    for (int i = tid; i < NANCH; i += 256) {
      float s = col[i];
      if (s >= 0.05f && bin0_of(s) == sel0)
        atomicAdd(&hist[bin1_of(s, lo)], 1u);
    }
    __syncthreads();
    if (tid == 0) {
      unsigned int cum = (unsigned int)s_cumabove; int sel = 0;
      for (int bin = NBINS - 1; bin >= 0; --bin) {
        unsigned int c = hist[bin];
        if (cum + c >= TOPK) { sel = bin; break; }
        cum += c;
      }
      s_sel1 = sel;
    }
    __syncthreads();
    sel1 = s_sel1;
  }

  // ---- collection: key >= (sel0, sel1) lexicographic ----
  if (tid == 0) s_ncand = 0;
  __syncthreads();
  for (int i = tid; i < NANCH; i += 256) {
    float s = col[i];
    if (s < 0.05f) continue;
    bool take;
    if (fallback) take = true;
    else {
      int b0 = bin0_of(s);
      take = (b0 > sel0) || (b0 == sel0 && bin1_of(s, lo) >= sel1);
    }
    if (take) {
      int pos = atomicAdd(&s_ncand, 1);
      if (pos < CAP) {
        unsigned int key = __float_as_uint(s) | 0x80000000u;  // s > 0 always
        cand[pos] = ((unsigned long long)(key ^ 0xFFFFFFFFu) << 32) |
                    (unsigned long long)(unsigned int)i;
      }
    }
  }
  __syncthreads();
  int ncand = s_ncand; if (ncand > CAP) ncand = CAP;
  for (int i = tid; i < CAP; i += 256) if (i >= ncand) cand[i] = ~0ULL;
  __syncthreads();

  // ---- bitonic sort 256 u64 ascending = (score desc, idx asc) ----
  for (int k = 2; k <= CAP; k <<= 1) {
    for (int j = k >> 1; j > 0; j >>= 1) {
      int partner = tid ^ j;
      unsigned long long mine = cand[tid];
      unsigned long long theirs = cand[partner];
      bool dirUp = ((tid & k) == 0);
      bool keepMin = (tid < partner) == dirUp;
      unsigned long long sel = ((mine < theirs) == keepMin) ? mine : theirs;
      __syncthreads();
      cand[tid] = sel;
      __syncthreads();
    }
  }
  const int nsel = (ncand < TOPK) ? ncand : TOPK;

  // ---- gather + decode (exact reference op order) ----
  if (tid < TOPK) {
    if (tid < nsel) {
      unsigned long long sk = cand[tid];
      unsigned int key = (unsigned int)(sk >> 32) ^ 0xFFFFFFFFu;
      float s = __uint_as_float(key ^ 0x80000000u);
      int idx = (int)(unsigned int)(sk & 0xFFFFFFFFu);
      float4 anc = ((const float4*)anchors)[idx];
      float4 l   = ((const float4*)loc)[(long long)b * NANCH + idx];
      float cx = anc.x + (l.x * 0.1f) * anc.z;
      float cy = anc.y + (l.y * 0.1f) * anc.w;
      float w  = anc.z * expf(l.z * 0.2f);
      float h  = anc.w * expf(l.w * 0.2f);
      float x1 = cx - 0.5f * w, y1 = cy - 0.5f * h;
      float x2 = cx + 0.5f * w, y2 = cy + 0.5f * h;
      bx[tid][0] = x1; bx[tid][1] = y1; bx[tid][2] = x2; bx[tid][3] = y2;
      barea[tid] = fmaxf(x2 - x1, 0.0f) * fmaxf(y2 - y1, 0.0f);
      bscore[tid] = s;
    } else {
      bx[tid][0] = bx[tid][1] = bx[tid][2] = bx[tid][3] = 0.0f;
      barea[tid] = 0.0f; bscore[tid] = 0.0f;
    }
  }
  __syncthreads();

  // ---- IoU adjacency bitmask (row t: bit j set iff IoU(t,j) > 0.5) ----
  if (tid < TOPK) {
    float ax1 = bx[tid][0], ay1 = bx[tid][1], ax2 = bx[tid][2], ay2 = bx[tid][3];
    float aar = barea[tid];
    for (int w = 0; w < 4; ++w) {
      unsigned long long mword = 0;
      int lim = (w < 3) ? 64 : (TOPK - 192);
      for (int jj = 0; jj < lim; ++jj) {
        int j = (w << 6) + jj;
        float ltx = fmaxf(ax1, bx[j][0]);
        float lty = fmaxf(ay1, bx[j][1]);
        float rbx = fminf(ax2, bx[j][2]);
        float rby = fminf(ay2, bx[j][3]);
        float iw = fmaxf(rbx - ltx, 0.0f);
        float ih = fmaxf(rby - lty, 0.0f);
        float inter = iw * ih;
        float uni = aar + barea[j] - inter;
        float iou = inter / fmaxf(uni, 1e-9f);
        if (iou > 0.5f) mword |= (1ULL << jj);
      }
      adj[tid][w] = mword;
    }
  }
  __syncthreads();

  // ---- serial greedy NMS with bitsets (thread 0) ----
  if (tid == 0) {
    unsigned long long s0 = 0, s1 = 0, s2 = 0, s3 = 0;
    for (int i = 0; i < 64; ++i) {
      bool kept = (i < nsel) && !((s0 >> i) & 1ULL);
      keepf[i] = kept ? 1 : 0;
      if (kept) { s0 |= adj[i][0]; s1 |= adj[i][1]; s2 |= adj[i][2]; s3 |= adj[i][3]; }
    }
    for (int i = 64; i < 128; ++i) {
      bool kept = (i < nsel) && !((s1 >> (i - 64)) & 1ULL);
      keepf[i] = kept ? 1 : 0;
      if (kept) { s0 |= adj[i][0]; s1 |= adj[i][1]; s2 |= adj[i][2]; s3 |= adj[i][3]; }
    }
    for (int i = 128; i < 192; ++i) {
      bool kept = (i < nsel) && !((s2 >> (i - 128)) & 1ULL);
      keepf[i] = kept ? 1 : 0;
      if (kept) { s0 |= adj[i][0]; s1 |= adj[i][1]; s2 |= adj[i][2]; s3 |= adj[i][3]; }
    }
    for (int i = 192; i < TOPK; ++i) {
      bool kept = (i < nsel) && !((s3 >> (i - 192)) & 1ULL);
      keepf[i] = kept ? 1 : 0;
      if (kept) { s0 |= adj[i][0]; s1 |= adj[i][1]; s2 |= adj[i][2]; s3 |= adj[i][3]; }
    }
  }
  __syncthreads();

  // ---- output: (B, 20, 200, 5) ----
  if (tid < TOPK) {
    float* o = out + ((long long)bc * TOPK + tid) * 5;
    bool k = keepf[tid] != 0;
    o[0] = k ? bx[tid][0] : 0.0f;
    o[1] = k ? bx[tid][1] : 0.0f;
    o[2] = k ? bx[tid][2] : 0.0f;
    o[3] = k ? bx[tid][3] : 0.0f;
    o[4] = k ? bscore[tid] : 0.0f;
  }
}

extern "C" void kernel_launch(void* const* d_in, const int* in_sizes, int n_in,
                              void* d_out, int out_size, void* d_ws, size_t ws_size,
                              hipStream_t stream) {
  const float* conf    = (const float*)d_in[0];
  const float* loc     = (const float*)d_in[1];
  const float* anchors = (const float*)d_in[2];
  float* out    = (float*)d_out;
  float* scores = (float*)d_ws;   // needs NB*NCLS*NANCH*4 = 83,886,080 bytes

  softmax_scores_kernel<<<(NB * NANCH) / 256, 256, 0, stream>>>(conf, scores);
  topk_nms_kernel<<<NB * NCLS, 256, 0, stream>>>(scores, loc, anchors, out);
}